// Round 12
// baseline (75.094 us; speedup 1.0000x reference)
//
#include <hip/hip_runtime.h>

#define FC    75               // K*K*C floats per pixel
#define GP    64               // pixels per group = lanes per wave
#define SLABF 4864             // 1216 float4: 1200 data + 16 pad for clamp tail
#define GPB   16               // groups per block

typedef float f32x4 __attribute__((ext_vector_type(4), aligned(4)));

// R8 ordered depth-2 pipeline + R11's NT staging (aux=2).
// 1024 persistent blocks x 64 threads (1 wave), 16 groups each, 4 blocks/CU.
// Per iteration: img(k)->regs FIRST, then 19x NT global_load_lds for k+1,
// then s_waitcnt vmcnt(19): in-order retirement => img(k)+slab(k) landed
// while the 19 prefetch loads stay in flight through compute. No wave ever
// has zero outstanding loads -> no dead HBM windows (R11's 30% residual).

__global__ __launch_bounds__(64, 1)
void convolve_kernel(const float* __restrict__ img,
                     const float* __restrict__ filts,
                     float* __restrict__ out)
{
    __shared__ float slabA[SLABF];
    __shared__ float slabB[SLABF];

    const int lane = threadIdx.x;          // 0..63

    // bijective XCD-chunked swizzle (1024 % 8 == 0)
    const int wgid = ((int)blockIdx.x & 7) * 128 + ((int)blockIdx.x >> 3);
    const int g0   = wgid * GPB;

    // stage one group's 4800 filts floats (1200 float4) into a slab, NT reads
    auto stage = [&](float* slab, int g) {
        const f32x4* src4 = (const f32x4*)(filts + (size_t)g * (GP * FC));
        #pragma unroll
        for (int j = 0; j < 19; ++j) {
            int idx4 = j * 64 + lane;
            idx4 = idx4 > 1199 ? 1199 : idx4;   // clamp tail (lands in pad)
            __builtin_amdgcn_global_load_lds(
                (const __attribute__((address_space(1))) void*)(src4 + idx4),
                (__attribute__((address_space(3))) void*)(slab + j * 256),
                16, 0, /*aux=NT*/ 2);
        }
    };

    stage(slabA, g0);                       // prologue: fill first slab
    float* cur = slabA;
    float* nxt = slabB;

    #pragma unroll 1
    for (int k = 0; k < GPB; ++k) {
        const int g  = g0 + k;
        const int p  = g * GP + lane;       // 64 consecutive pixels, same row
        const int b  = p >> 18;
        const int hw = p & ((1 << 18) - 1);
        const int h  = hw >> 9;
        const int w  = hw & 511;
        const float* imgb = img + (size_t)b * (512u * 512u * 3u);

        // ---- 1. img(k) -> regs, BEFORE the prefetch (in-order vmcnt) ----
        f32x4 v[5][4];
        #pragma unroll
        for (int di = 0; di < 5; ++di)
            #pragma unroll
            for (int jj = 0; jj < 4; ++jj)
                v[di][jj] = (f32x4)0.f;

        const int gm8 = g & 7;
        if (gm8 != 0 && gm8 != 7) {
            // fully w-interior group: 4x f32x4 per valid row (15 of 16 used)
            const float* q0 = imgb + (w - 2) * 3;
            #pragma unroll
            for (int di = 0; di < 5; ++di) {
                const int hh = h + di - 2;
                if ((unsigned)hh < 512u) {  // wave-uniform
                    const float* q = q0 + (size_t)hh * 1536;
                    v[di][0] = *(const f32x4*)(q);
                    v[di][1] = *(const f32x4*)(q + 4);
                    v[di][2] = *(const f32x4*)(q + 8);
                    v[di][3] = *(const f32x4*)(q + 12);
                }
            }
        } else {
            // row-edge group: guarded scalar loads into zeroed regs
            #pragma unroll
            for (int di = 0; di < 5; ++di) {
                const int hh = h + di - 2;
                if ((unsigned)hh < 512u) {
                    const float* row = imgb + (size_t)hh * 1536;
                    #pragma unroll
                    for (int dj = 0; dj < 5; ++dj) {
                        const int ww = w + dj - 2;
                        if ((unsigned)ww < 512u) {
                            const float* px = row + ww * 3;
                            #pragma unroll
                            for (int c = 0; c < 3; ++c) {
                                const int idx = dj * 3 + c;
                                v[di][idx >> 2][idx & 3] = px[c];
                            }
                        }
                    }
                }
            }
        }
        __builtin_amdgcn_sched_barrier(0);  // img issue stays ABOVE prefetch

        // ---- 2. prefetch filts(k+1) into the other slab ----
        if (k + 1 < GPB) {
            stage(nxt, g + 1);
            // ---- 3. all but the 19 newest (the prefetch) retired ----
            asm volatile("s_waitcnt vmcnt(19)" ::: "memory");
        } else {
            asm volatile("s_waitcnt vmcnt(0)" ::: "memory");
        }
        __builtin_amdgcn_sched_barrier(0);  // rule #18: ds_reads stay below

        // ---- 4. compute group k: LDS filts x reg img ----
        const float* fp = cur + lane * FC;  // stride 75 dw -> 2/bank, free
        float a0 = 0.f, a1 = 0.f, a2 = 0.f;
        #pragma unroll
        for (int di = 0; di < 5; ++di) {
            const float* fr = fp + di * 15;
            a0 += v[di][0].x * fr[0];  a1 += v[di][0].y * fr[1];  a2 += v[di][0].z * fr[2];
            a0 += v[di][0].w * fr[3];  a1 += v[di][1].x * fr[4];  a2 += v[di][1].y * fr[5];
            a0 += v[di][1].z * fr[6];  a1 += v[di][1].w * fr[7];  a2 += v[di][2].x * fr[8];
            a0 += v[di][2].y * fr[9];  a1 += v[di][2].z * fr[10]; a2 += v[di][2].w * fr[11];
            a0 += v[di][3].x * fr[12]; a1 += v[di][3].y * fr[13]; a2 += v[di][3].z * fr[14];
        }
        __builtin_nontemporal_store(a0 + a1 + a2, out + p);

        float* t = cur; cur = nxt; nxt = t;
    }
}

extern "C" void kernel_launch(void* const* d_in, const int* in_sizes, int n_in,
                              void* d_out, int out_size, void* d_ws, size_t ws_size,
                              hipStream_t stream)
{
    const float* img   = (const float*)d_in[0];   // [4,512,512,3]  f32
    const float* filts = (const float*)d_in[1];   // [4,512,512,75] f32
    float* out         = (float*)d_out;           // [4,512,512]    f32

    // 16384 groups / 16 per block = 1024 blocks of 64 threads (4/CU by LDS)
    convolve_kernel<<<1024, 64, 0, stream>>>(img, filts, out);
}

// Round 13
// 64.446 us; speedup vs baseline: 1.1652x; 1.1652x over previous
//
#include <hip/hip_runtime.h>

#define FC    75               // K*K*C floats per pixel
#define GPX   32               // pixels per group (2 lanes per pixel)
#define SLABF 2400             // 32 px * 75 floats = 9600 B -> 16 slabs/CU

typedef float f32x4 __attribute__((ext_vector_type(4), aligned(4)));

// 32768 blocks x 64 threads (1 wave). Wave = 32 pixels, 2 lanes/pixel:
// half 0 -> taps 0..11, half 1 -> taps 12..24 (12 uniform-shape taps via
// constant tables selected on `half`, + 1 exec-masked tap for half 1).
// Slab 9.6 KB -> 16 independent stage/compute waves per CU (2x R11, the
// wave-count lever: 4 waves=4.4 TB/s, 8 waves=4.85 TB/s measured).
// Staging: NT (aux=2) width-16 global_load_lds, 9 full + 1 masked.

__global__ __launch_bounds__(64, 4)
void convolve_kernel(const float* __restrict__ img,
                     const float* __restrict__ filts,
                     float* __restrict__ out)
{
    __shared__ float slab[SLABF];

    const int lane = threadIdx.x;          // 0..63
    const int half = lane & 1;
    const int pxi  = lane >> 1;            // 0..31

    // bijective XCD-chunked swizzle (32768 % 8 == 0)
    const int g = ((int)blockIdx.x & 7) * 4096 + ((int)blockIdx.x >> 3);

    // ---- stage this group's 2400 filts floats (600 float4) into LDS ----
    {
        const f32x4* src4 = (const f32x4*)(filts + (size_t)g * (GPX * FC));
        #pragma unroll
        for (int j = 0; j < 9; ++j) {
            __builtin_amdgcn_global_load_lds(
                (const __attribute__((address_space(1))) void*)(src4 + j * 64 + lane),
                (__attribute__((address_space(3))) void*)(slab + j * 256),
                16, 0, /*aux=NT*/ 2);
        }
        if (lane < 24) {                    // tail: 576..599 (exec-masked)
            __builtin_amdgcn_global_load_lds(
                (const __attribute__((address_space(1))) void*)(src4 + 576 + lane),
                (__attribute__((address_space(3))) void*)(slab + 9 * 256),
                16, 0, /*aux=NT*/ 2);
        }
    }
    asm volatile("s_waitcnt vmcnt(0)" ::: "memory");
    __builtin_amdgcn_sched_barrier(0);      // rule #18: ds_reads stay below wait

    // ---- compute: 2 lanes per pixel ----
    const int p  = g * GPX + pxi;           // 32 consecutive pixels, same row
    const int b  = p >> 18;                 // / (512*512)
    const int hw = p & ((1 << 18) - 1);
    const int h  = hw >> 9;
    const int w  = hw & 511;

    // this lane's filter base: pixel pxi, tap block half*12 (dword 36 offset)
    const float* fp   = slab + pxi * FC + half * 36;
    const float* imgb = img + (size_t)b * (512u * 512u * 3u);

    // tap tables: half0 -> taps 0..11, half1 -> taps 12..23 (tap 24 masked)
    const int DI0[12] = {0,0,0,0,0,1,1,1,1,1,2,2};
    const int DJ0[12] = {0,1,2,3,4,0,1,2,3,4,0,1};
    const int DI1[12] = {2,2,2,3,3,3,3,3,4,4,4,4};
    const int DJ1[12] = {2,3,4,0,1,2,3,4,0,1,2,3};

    float a0 = 0.f, a1 = 0.f, a2 = 0.f;
    #pragma unroll
    for (int t = 0; t < 12; ++t) {
        const int di = half ? DI1[t] : DI0[t];   // cndmask of constants
        const int dj = half ? DJ1[t] : DJ0[t];
        const int hh = h + di - 2;
        const int ww = w + dj - 2;
        if (((unsigned)hh < 512u) && ((unsigned)ww < 512u)) {
            const float* px = imgb + (size_t)hh * 1536 + ww * 3;
            const float* fr = fp + t * 3;
            a0 += px[0] * fr[0];
            a1 += px[1] * fr[1];
            a2 += px[2] * fr[2];
        }
    }
    if (half) {                              // tap 24 (di=4, dj=4), fr dwords 72..74
        const int hh = h + 2;
        const int ww = w + 2;
        if (((unsigned)hh < 512u) && ((unsigned)ww < 512u)) {
            const float* px = imgb + (size_t)hh * 1536 + ww * 3;
            const float* fr = fp + 36;       // fp already at +36 for half1 -> dword 72
            a0 += px[0] * fr[0];
            a1 += px[1] * fr[1];
            a2 += px[2] * fr[2];
        }
    }

    // combine lane pair and store (even lanes -> 32 consecutive dwords)
    const float mine = a0 + a1 + a2;
    const float peer = __shfl_xor(mine, 1, 64);
    if (!half) out[p] = mine + peer;
}

extern "C" void kernel_launch(void* const* d_in, const int* in_sizes, int n_in,
                              void* d_out, int out_size, void* d_ws, size_t ws_size,
                              hipStream_t stream)
{
    const float* img   = (const float*)d_in[0];   // [4,512,512,3]  f32
    const float* filts = (const float*)d_in[1];   // [4,512,512,75] f32
    float* out         = (float*)d_out;           // [4,512,512]    f32

    // 1,048,576 pixels / 32 per block = 32768 blocks of 64 threads
    convolve_kernel<<<32768, 64, 0, stream>>>(img, filts, out);
}